// Round 1
// baseline (874.811 us; speedup 1.0000x reference)
//
#include <hip/hip_runtime.h>

// ---------- helpers ----------
typedef __bf16 bf16x8 __attribute__((ext_vector_type(8)));
typedef float  f32x4  __attribute__((ext_vector_type(4)));

static __device__ __forceinline__ unsigned short f32_to_bf16(float f) {
  union { float f; unsigned u; } v; v.f = f;
  unsigned r = v.u + 0x7fffu + ((v.u >> 16) & 1u);   // RNE
  return (unsigned short)(r >> 16);
}

// ---------- L,R f32 -> bf16 (natural layout; both are already MFMA-A-friendly) ----------
__global__ __launch_bounds__(256) void k_cvt2(const float* __restrict__ L,
                                              const float* __restrict__ R,
                                              unsigned short* __restrict__ Lb,
                                              unsigned short* __restrict__ Rb) {
  int i = blockIdx.x * 256 + threadIdx.x;          // 0..1048575 over two 524288-float4 tensors
  const float* s; unsigned short* d; int idx;
  if (i < 524288) { s = L; d = Lb; idx = i; } else { s = R; d = Rb; idx = i - 524288; }
  float4 v = ((const float4*)s)[idx];
  uint2 o;
  o.x = (unsigned)f32_to_bf16(v.x) | ((unsigned)f32_to_bf16(v.y) << 16);
  o.y = (unsigned)f32_to_bf16(v.z) | ((unsigned)f32_to_bf16(v.w) << 16);
  ((uint2*)d)[idx] = o;
}

// ---------- Stage A (fused transpose + block GEMM) ----------
// T[j][r][m] = sum_k L[m][j][k] * x[r][k*128+m]
// Block: 16 m x 16 r x all 128 j (2 phases of 64 j). Grid 2048, 1-D with XCD-pair decode
// so the two blocks sharing each 64B T-line (m-chunk pair) land on the same XCD, 8 slots apart.
__global__ __launch_bounds__(256, 2) void k_stageA(const float* __restrict__ x,
                                                   const unsigned short* __restrict__ Lb,
                                                   unsigned short* __restrict__ T) {
  __shared__ unsigned short Xs[16 * 16 * 128];     // [m][r][k] bf16, chunk^r swizzle, 64 KB
  const int bid = blockIdx.x;
  const int u = bid & 7, h = (bid >> 3) & 1, t = (bid >> 4) & 31, P = bid >> 9;
  const int r0 = ((t << 3) + u) << 4;              // r-tile: 0..255 -> *16
  const int m0 = ((P << 1) + h) << 4;              // m-chunk: 0..7  -> *16
  const int tid = threadIdx.x;
  const int w = tid >> 6, lane = tid & 63;

  { // stage x[r0..+15][k*128 + m0..+15] -> Xs, register micro-transpose + bf16 cvt.
    // Lane order (mg fastest): 4 lanes cover one full 64B line -> x lines read exactly once.
    const int mg = tid & 3, kg = (tid >> 2) & 15;
#pragma unroll
    for (int it = 0; it < 4; ++it) {
      const int r = (it << 2) + w;
      const float* g = x + (size_t)(r0 + r) * 16384 + m0 + (mg << 2);
      float4 v[8];
#pragma unroll
      for (int kk = 0; kk < 8; ++kk) v[kk] = *(const float4*)(g + (((kg << 3) + kk) << 7));
      const int cw = (kg ^ r) << 3;
#pragma unroll
      for (int mm = 0; mm < 4; ++mm) {
        unsigned short o[8];
#pragma unroll
        for (int kk = 0; kk < 8; ++kk) o[kk] = f32_to_bf16(((const float*)&v[kk])[mm]);
        *(uint4*)&Xs[((((mg << 2) + mm) << 4) + r) * 128 + cw] = *(const uint4*)o;
      }
    }
  }
  __syncthreads();

  const int mh = w & 1, jh = w >> 1;               // wave = (m-half, j-half)
  const int l16 = lane & 15, q = lane >> 4;
  const unsigned short* Lw = Lb + (size_t)(m0 + (mh << 3)) * 16384 + (q << 3);

#pragma unroll
  for (int phase = 0; phase < 2; ++phase) {
    const int jb = (phase << 6) + (jh << 5);
    f32x4 acc[8][2] = {};
#pragma unroll
    for (int ks = 0; ks < 4; ++ks) {
      bf16x8 Af[2][8];                             // L[m][j][k] natural layout, L2-resident
#pragma unroll
      for (int jf = 0; jf < 2; ++jf)
#pragma unroll
        for (int mm = 0; mm < 8; ++mm)
          Af[jf][mm] = *(const bf16x8*)(Lw + (size_t)mm * 16384
                                        + ((jb + (jf << 4) + l16) << 7) + (ks << 5));
      bf16x8 Bf[8];
#pragma unroll
      for (int mm = 0; mm < 8; ++mm)
        Bf[mm] = *(const bf16x8*)&Xs[((((mh << 3) + mm) << 4) + l16) * 128
                                     + ((((ks << 2) + q) ^ l16) << 3)];
#pragma unroll
      for (int jf = 0; jf < 2; ++jf)
#pragma unroll
        for (int mm = 0; mm < 8; ++mm)
          acc[mm][jf] = __builtin_amdgcn_mfma_f32_16x16x32_bf16(Af[jf][mm], Bf[mm],
                                                                acc[mm][jf], 0, 0, 0);
    }
    // epilogue: lane holds T[j = jb+jf*16+q*4+p][r0+l16][m0+mh*8 .. +7] -> bf16x8 (16B)
#pragma unroll
    for (int jf = 0; jf < 2; ++jf)
#pragma unroll
      for (int p = 0; p < 4; ++p) {
        const int j = jb + (jf << 4) + (q << 2) + p;
        unsigned short o[8];
#pragma unroll
        for (int mm = 0; mm < 8; ++mm) o[mm] = f32_to_bf16(acc[mm][jf][p]);
        *(uint4*)(T + ((size_t)j * 4096 + r0 + l16) * 128 + m0 + (mh << 3)) = *(const uint4*)o;
      }
  }
}

// ---------- Stage B (block GEMM + fused bias + natural-layout store) ----------
// out[r][i*128+j] = sum_m R[j][i][m] * T[j][r][m] + bias[i*128+j]
// Block: 16 j x 16 r x all 128 i (2 phases of 64 i). Grid (256 rt, 8 jc).
__global__ __launch_bounds__(256, 2) void k_stageB(const unsigned short* __restrict__ T,
                                                   const unsigned short* __restrict__ Rb,
                                                   const float* __restrict__ bias,
                                                   float* __restrict__ out) {
  __shared__ unsigned short Ts[16 * 16 * 128];     // [jl][r][m] bf16, chunk^r swizzle, 64 KB
  const int r0 = blockIdx.x << 4;
  const int j0 = blockIdx.y << 4;
  const int tid = threadIdx.x;
  const int w = tid >> 6, lane = tid & 63;

  { // stage T slice: per (j,r) a fully contiguous 256B row; direct copy into swizzled slot.
    const int seg = tid & 15, r = tid >> 4;
    const int cw = (seg ^ r) << 3;
#pragma unroll
    for (int jl = 0; jl < 16; ++jl) {
      uint4 v = *(const uint4*)(T + ((size_t)(j0 + jl) * 4096 + r0 + r) * 128 + (seg << 3));
      *(uint4*)&Ts[((jl << 4) + r) * 128 + cw] = v;
    }
  }
  __syncthreads();

  const int jh = w & 1, ih = w >> 1;               // wave = (j-half, i-half)
  const int l16 = lane & 15, q = lane >> 4;
  const unsigned short* Rw = Rb + (size_t)(j0 + (jh << 3)) * 16384 + (l16 << 7) + (q << 3);

#pragma unroll
  for (int phase = 0; phase < 2; ++phase) {
    const int ib = (phase << 6) + (ih << 5);
    f32x4 acc[8][2] = {};
#pragma unroll
    for (int ms = 0; ms < 4; ++ms) {
      bf16x8 Af[2][8];                             // R[j][i][m] natural layout, L2-resident
#pragma unroll
      for (int ifr = 0; ifr < 2; ++ifr)
#pragma unroll
        for (int jj = 0; jj < 8; ++jj)
          Af[ifr][jj] = *(const bf16x8*)(Rw + (size_t)jj * 16384
                                         + ((ib + (ifr << 4)) << 7) + (ms << 5));
      bf16x8 Bf[8];
#pragma unroll
      for (int jj = 0; jj < 8; ++jj)
        Bf[jj] = *(const bf16x8*)&Ts[((((jh << 3) + jj) << 4) + l16) * 128
                                     + ((((ms << 2) + q) ^ l16) << 3)];
#pragma unroll
      for (int ifr = 0; ifr < 2; ++ifr)
#pragma unroll
        for (int jj = 0; jj < 8; ++jj)
          acc[jj][ifr] = __builtin_amdgcn_mfma_f32_16x16x32_bf16(Af[ifr][jj], Bf[jj],
                                                                 acc[jj][ifr], 0, 0, 0);
    }
    // epilogue: lane r = l16; 8 consecutive j floats per (i) -> two float4 stores + bias
#pragma unroll
    for (int ifr = 0; ifr < 2; ++ifr)
#pragma unroll
      for (int p = 0; p < 4; ++p) {
        const int i = ib + (ifr << 4) + (q << 2) + p;
        const size_t fb = (size_t)i * 128 + j0 + (jh << 3);
        const float4 b0 = *(const float4*)(bias + fb);
        const float4 b1 = *(const float4*)(bias + fb + 4);
        float4 o0, o1;
        o0.x = acc[0][ifr][p] + b0.x; o0.y = acc[1][ifr][p] + b0.y;
        o0.z = acc[2][ifr][p] + b0.z; o0.w = acc[3][ifr][p] + b0.w;
        o1.x = acc[4][ifr][p] + b1.x; o1.y = acc[5][ifr][p] + b1.y;
        o1.z = acc[6][ifr][p] + b1.z; o1.w = acc[7][ifr][p] + b1.w;
        float* op = out + (size_t)(r0 + l16) * 16384 + fb;
        *(float4*)op = o0;
        *(float4*)(op + 4) = o1;
      }
  }
}

extern "C" void kernel_launch(void* const* d_in, const int* in_sizes, int n_in,
                              void* d_out, int out_size, void* d_ws, size_t ws_size,
                              hipStream_t stream) {
  const float* x    = (const float*)d_in[0];   // 2*2048*16384 f32 (4096 rows)
  const float* L    = (const float*)d_in[1];   // 128^3 f32
  const float* R    = (const float*)d_in[2];   // 128^3 f32
  const float* bias = (const float*)d_in[3];   // 16384 f32
  float* out = (float*)d_out;

  // workspace: Lb 4M | Rb 4M | T 128M
  const size_t SZ_W = (size_t)4 << 20;
  const size_t SZ_T = (size_t)128 << 20;
  if (ws_size < 2 * SZ_W + SZ_T) return;       // fail loudly (poison stays)

  char* ws = (char*)d_ws;
  unsigned short* Lb = (unsigned short*)ws;
  unsigned short* Rb = (unsigned short*)(ws + SZ_W);
  unsigned short* Tw = (unsigned short*)(ws + 2 * SZ_W);

  k_cvt2<<<4096, 256, 0, stream>>>(L, R, Lb, Rb);
  k_stageA<<<2048, 256, 0, stream>>>(x, Lb, Tw);
  k_stageB<<<dim3(256, 8), 256, 0, stream>>>(Tw, Rb, bias, out);
}

// Round 3
// 770.354 us; speedup vs baseline: 1.1356x; 1.1356x over previous
//
#include <hip/hip_runtime.h>

// ---------- helpers ----------
typedef __bf16 bf16x8 __attribute__((ext_vector_type(8)));
typedef float  f32x4  __attribute__((ext_vector_type(4)));

static __device__ __forceinline__ unsigned short f32_to_bf16(float f) {
  union { float f; unsigned u; } v; v.f = f;
  unsigned r = v.u + 0x7fffu + ((v.u >> 16) & 1u);   // RNE
  return (unsigned short)(r >> 16);
}

// ---------- L,R f32 -> bf16 (natural layouts are already MFMA-friendly) ----------
__global__ __launch_bounds__(256) void k_cvt2(const float* __restrict__ L,
                                              const float* __restrict__ R,
                                              unsigned short* __restrict__ Lb,
                                              unsigned short* __restrict__ Rb) {
  int i = blockIdx.x * 256 + threadIdx.x;
  const float* s; unsigned short* d; int idx;
  if (i < 524288) { s = L; d = Lb; idx = i; } else { s = R; d = Rb; idx = i - 524288; }
  float4 v = ((const float4*)s)[idx];
  uint2 o;
  o.x = (unsigned)f32_to_bf16(v.x) | ((unsigned)f32_to_bf16(v.y) << 16);
  o.y = (unsigned)f32_to_bf16(v.z) | ((unsigned)f32_to_bf16(v.w) << 16);
  ((uint2*)d)[idx] = o;
}

// ---------- Stage A ----------
// T[m][j][r] = sum_k L[m][j][k] * x[r][k*128+m]
// Block: m-chunk 16 (bid&7 -> XCD-specialized L slice), r-tile 32, j/k full.
// MFMA orientation M=r, N=j so lane's 4 acc regs = 4 consecutive r -> packed 8B T-stores;
// rf=0/1 back-to-back stores complete each 64B T line (32 r = block r-tile) within one wave.
__global__ __launch_bounds__(256, 1) void k_stageA(const float* __restrict__ x,
                                                   const unsigned short* __restrict__ Lb,
                                                   unsigned short* __restrict__ T) {
  __shared__ unsigned short Xs[65536];   // [m16][r32][k128] bf16 (128 KiB); chunk c at c^(r&15)
  const int bid = blockIdx.x;
  const int m0 = (bid & 7) << 4;
  const int r0 = (bid >> 3) << 5;
  const int tid = threadIdx.x;
  const int w = tid >> 6, lane = tid & 63;

  { // stage x[r0..+31][k*128+m0..+15]: 4 lanes cover each 64B line; transpose to k-major bf16
    const int mg = lane & 3, kg = lane >> 2;
#pragma unroll
    for (int it = 0; it < 8; ++it) {
      const int r = (it << 2) + w;
      const float* g = x + (size_t)(r0 + r) * 16384 + m0 + (mg << 2);
      float4 v[8];
#pragma unroll
      for (int kk = 0; kk < 8; ++kk) v[kk] = *(const float4*)(g + (((kg << 3) + kk) << 7));
      const int cw = (kg ^ (r & 15)) << 3;
#pragma unroll
      for (int mm = 0; mm < 4; ++mm) {
        unsigned short o[8];
#pragma unroll
        for (int kk = 0; kk < 8; ++kk) o[kk] = f32_to_bf16(((const float*)&v[kk])[mm]);
        *(uint4*)&Xs[((((mg << 2) + mm) << 5) + r) * 128 + cw] = *(const uint4*)o;
      }
    }
  }
  __syncthreads();

  const int l16 = lane & 15, q = lane >> 4;
  const int mloc = w << 2;               // wave owns 4 m-batches
#pragma unroll
  for (int jt = 0; jt < 8; ++jt) {
    const int j0 = jt << 4;
    f32x4 acc[4][2] = {};                // [mi][rf]
#pragma unroll
    for (int ks = 0; ks < 4; ++ks) {
#pragma unroll
      for (int mi = 0; mi < 4; ++mi) {
        // B operand (N=j): L[m][j0+l16][ks*32+q*8..] — natural layout, L2-hot
        const bf16x8 bfrag = *(const bf16x8*)(Lb + (size_t)(m0 + mloc + mi) * 16384
                                              + ((j0 + l16) << 7) + (ks << 5) + (q << 3));
#pragma unroll
        for (int rf = 0; rf < 2; ++rf) {
          // A operand (M=r): Xs[m][rf*16+l16][k], swizzled
          const int row = ((mloc + mi) << 5) + (rf << 4) + l16;
          const bf16x8 afrag = *(const bf16x8*)&Xs[row * 128 + ((((ks << 2) + q) ^ l16) << 3)];
          acc[mi][rf] = __builtin_amdgcn_mfma_f32_16x16x32_bf16(afrag, bfrag, acc[mi][rf], 0, 0, 0);
        }
      }
    }
    // epilogue: lane writes T[m][j0+l16][r0 + rf*16 + q*4 .. +3] as packed 8B; rf pair -> 64B line
#pragma unroll
    for (int mi = 0; mi < 4; ++mi) {
      unsigned short* tp = T + (size_t)(m0 + mloc + mi) * 524288
                             + ((size_t)(j0 + l16) << 12) + r0 + (q << 2);
#pragma unroll
      for (int rf = 0; rf < 2; ++rf) {
        unsigned short o[4];
#pragma unroll
        for (int p = 0; p < 4; ++p) o[p] = f32_to_bf16(acc[mi][rf][p]);
        *(uint2*)(tp + (rf << 4)) = *(const uint2*)o;
      }
    }
  }
}

// ---------- Stage B ----------
// out[r][i*128+j] = sum_m R[j][i][m] * T[m][j][r] + bias
// Block: j-tile 16 (bid&7 -> XCD-specialized R slice), r-tile 32, i full (2 phases x 4 waves x 16).
// MFMA orientation M=i, N=r with j as acc-batch: lane owns a FULL 64B out line
// (16 consecutive j for fixed r,i), stored as 4 back-to-back float4 with fused bias.
__global__ __launch_bounds__(256, 1) void k_stageB(const unsigned short* __restrict__ T,
                                                   const unsigned short* __restrict__ Rb,
                                                   const float* __restrict__ bias,
                                                   float* __restrict__ out) {
  __shared__ unsigned short Ts[65536];   // [j16][r32][m128] bf16 (128 KiB); chunk c at c^(row&15)
  const int bid = blockIdx.x;
  const int j0 = (bid & 7) << 4;
  const int r0 = (bid >> 3) << 5;
  const int tid = threadIdx.x;

  { // stage T[m][j0..+15][r0..+31]: full 64B-line reads; 8x8 (m x r) register transpose
#pragma unroll
    for (int it = 0; it < 4; ++it) {
      const int flat = (it << 8) + tid;
      const int rc = flat & 3, jj = (flat >> 2) & 15, mc = flat >> 6;   // mc 0..15
      uint4 v[8];
#pragma unroll
      for (int mm = 0; mm < 8; ++mm)
        v[mm] = *(const uint4*)(T + (size_t)((mc << 3) + mm) * 524288
                                + ((size_t)(j0 + jj) << 12) + r0 + (rc << 3));
      const unsigned short* s = (const unsigned short*)v;
#pragma unroll
      for (int rr = 0; rr < 8; ++rr) {
        unsigned short o[8];
#pragma unroll
        for (int mm = 0; mm < 8; ++mm) o[mm] = s[(mm << 3) + rr];
        const int row = (jj << 5) + (rc << 3) + rr;
        *(uint4*)&Ts[row * 128 + ((mc ^ (row & 15)) << 3)] = *(const uint4*)o;
      }
    }
  }
  __syncthreads();

  const int w = tid >> 6, lane = tid & 63, l16 = lane & 15, q = lane >> 4;
#pragma unroll
  for (int ph = 0; ph < 2; ++ph) {
    const int ib = (ph << 6) + (w << 4);
    f32x4 acc[16][2] = {};               // [jb][rf] — j is the accumulator batch
#pragma unroll
    for (int ms = 0; ms < 4; ++ms) {
#pragma unroll
      for (int jb = 0; jb < 16; ++jb) {
        // A operand (M=i): R[j0+jb][ib+l16][ms*32+q*8..] — natural layout, L2-hot
        const bf16x8 af = *(const bf16x8*)(Rb + (size_t)(j0 + jb) * 16384
                                           + ((ib + l16) << 7) + (ms << 5) + (q << 3));
#pragma unroll
        for (int rf = 0; rf < 2; ++rf) {
          const int row = (jb << 5) + (rf << 4) + l16;
          const bf16x8 bf = *(const bf16x8*)&Ts[row * 128 + ((((ms << 2) + q) ^ l16) << 3)];
          acc[jb][rf] = __builtin_amdgcn_mfma_f32_16x16x32_bf16(af, bf, acc[jb][rf], 0, 0, 0);
        }
      }
    }
    // epilogue: lane writes out[r][i*128 + j0..+15] = full 64B line, bias fused
#pragma unroll
    for (int p = 0; p < 4; ++p) {
      const int i = ib + (q << 2) + p;
      const float* bp = bias + (i << 7) + j0;
      const float4 b0 = *(const float4*)(bp + 0), b1 = *(const float4*)(bp + 4),
                   b2 = *(const float4*)(bp + 8), b3 = *(const float4*)(bp + 12);
#pragma unroll
      for (int rf = 0; rf < 2; ++rf) {
        float* op = out + ((size_t)(r0 + (rf << 4) + l16) << 14) + (i << 7) + j0;
        float4 o0, o1, o2, o3;
        o0.x = acc[0][rf][p] + b0.x;  o0.y = acc[1][rf][p] + b0.y;
        o0.z = acc[2][rf][p] + b0.z;  o0.w = acc[3][rf][p] + b0.w;
        o1.x = acc[4][rf][p] + b1.x;  o1.y = acc[5][rf][p] + b1.y;
        o1.z = acc[6][rf][p] + b1.z;  o1.w = acc[7][rf][p] + b1.w;
        o2.x = acc[8][rf][p] + b2.x;  o2.y = acc[9][rf][p] + b2.y;
        o2.z = acc[10][rf][p] + b2.z; o2.w = acc[11][rf][p] + b2.w;
        o3.x = acc[12][rf][p] + b3.x; o3.y = acc[13][rf][p] + b3.y;
        o3.z = acc[14][rf][p] + b3.z; o3.w = acc[15][rf][p] + b3.w;
        *(float4*)(op + 0)  = o0; *(float4*)(op + 4)  = o1;
        *(float4*)(op + 8)  = o2; *(float4*)(op + 12) = o3;
      }
    }
  }
}

extern "C" void kernel_launch(void* const* d_in, const int* in_sizes, int n_in,
                              void* d_out, int out_size, void* d_ws, size_t ws_size,
                              hipStream_t stream) {
  const float* x    = (const float*)d_in[0];   // 4096 x 16384 f32
  const float* L    = (const float*)d_in[1];   // 128^3 f32  [m][j][k]
  const float* R    = (const float*)d_in[2];   // 128^3 f32  [j][i][m]
  const float* bias = (const float*)d_in[3];   // 16384 f32
  float* out = (float*)d_out;

  // workspace: Lb 4M | Rb 4M | T 128M  (T[m][j][r] bf16)
  const size_t SZ_W = (size_t)4 << 20;
  const size_t SZ_T = (size_t)128 << 20;
  if (ws_size < 2 * SZ_W + SZ_T) return;       // fail loudly (poison stays)

  char* ws = (char*)d_ws;
  unsigned short* Lb = (unsigned short*)ws;
  unsigned short* Rb = (unsigned short*)(ws + SZ_W);
  unsigned short* Tw = (unsigned short*)(ws + 2 * SZ_W);

  k_cvt2<<<4096, 256, 0, stream>>>(L, R, Lb, Rb);
  k_stageA<<<1024, 256, 0, stream>>>(x, Lb, Tw);          // 128 r-tiles x 8 m-chunks
  k_stageB<<<1024, 256, 0, stream>>>(Tw, Rb, bias, out);  // 128 r-tiles x 8 j-chunks
}